// Round 4
// baseline (188.988 us; speedup 1.0000x reference)
//
#include <hip/hip_runtime.h>
#include <math.h>

#define NN 1024
#define CC 256
#define TT 64

typedef __attribute__((ext_vector_type(8))) short bf16x8;  // 8 bf16 (4 VGPRs)
typedef __attribute__((ext_vector_type(4))) float f32x4;   // MFMA accumulator

// round-to-nearest-even fp32 -> bf16 bits
__device__ __forceinline__ ushort f2bf(float f) {
  unsigned u = __float_as_uint(f);
  return (ushort)((u + 0x7fffu + ((u >> 16) & 1u)) >> 16);
}
__device__ __forceinline__ float bf2f(ushort b) {
  return __uint_as_float(((unsigned)b) << 16);
}

// ---------------- kernel 1: time-mean + norms + bf16 hi/lo split ----------------
// 2048 blocks: block b -> tensor (b>>10), row (b&1023). Reads contiguous 64KB.
// All 16 float4 loads issued before any use -> 16KB/wave in flight (HBM-sat).
// Also zeroes the dist kernel's atomic accumulators (blocks 0..8).
__global__ __launch_bounds__(256) void mean_norm_kernel(
    const float* __restrict__ in0, const float* __restrict__ in1,
    ushort* __restrict__ xh, ushort* __restrict__ xl,
    ushort* __restrict__ yh, ushort* __restrict__ yl,
    float* __restrict__ nx, float* __restrict__ ny,
    float* __restrict__ Rx, float* __restrict__ Ry,
    float* __restrict__ sums, unsigned* __restrict__ counter) {
  int b = blockIdx.x;
  int tid = threadIdx.x;

  // init duties for the fused dist+finalize kernel (runs strictly later)
  if (b < 4) Rx[b * 256 + tid] = 0.f;
  else if (b < 8) Ry[(b - 4) * 256 + tid] = 0.f;
  else if (b == 8) { if (tid < 3) sums[tid] = 0.f; if (tid == 3) *counter = 0u; }

  int m = b >> 10;
  int n = b & (NN - 1);
  const float4* src = (const float4*)((m ? in1 : in0) + (size_t)n * (TT * CC)) + (tid & 63);
  int c4 = tid & 63;
  int tq = tid >> 6;

  float4 v[16];
  #pragma unroll
  for (int t = 0; t < 16; ++t) v[t] = src[(tq * 16 + t) * (CC / 4)];
  #pragma unroll
  for (int h = 8; h > 0; h >>= 1)
    #pragma unroll
    for (int i = 0; i < h; ++i) {
      v[i].x += v[i + h].x; v[i].y += v[i + h].y;
      v[i].z += v[i + h].z; v[i].w += v[i + h].w;
    }
  float4 s = v[0];

  __shared__ float4 red[3][64];
  if (tq) red[tq - 1][c4] = s;
  __syncthreads();
  if (tq == 0) {
    #pragma unroll
    for (int w = 0; w < 3; ++w) {
      float4 t = red[w][c4];
      s.x += t.x; s.y += t.y; s.z += t.z; s.w += t.w;
    }
    const float inv = 1.0f / TT;
    s.x *= inv; s.y *= inv; s.z *= inv; s.w *= inv;

    ushort* ho = m ? yh : xh;
    ushort* lo = m ? yl : xl;
    ushort4 h4, l4;
    h4.x = f2bf(s.x); l4.x = f2bf(s.x - bf2f(h4.x));
    h4.y = f2bf(s.y); l4.y = f2bf(s.y - bf2f(h4.y));
    h4.z = f2bf(s.z); l4.z = f2bf(s.z - bf2f(h4.z));
    h4.w = f2bf(s.w); l4.w = f2bf(s.w - bf2f(h4.w));
    ((ushort4*)(ho + (size_t)n * CC))[c4] = h4;
    ((ushort4*)(lo + (size_t)n * CC))[c4] = l4;

    float ssq = fmaf(s.x, s.x, fmaf(s.y, s.y, fmaf(s.z, s.z, s.w * s.w)));
    #pragma unroll
    for (int o = 32; o > 0; o >>= 1) ssq += __shfl_down(ssq, o, 64);
    if (tid == 0) (m ? ny : nx)[n] = ssq;
  }
}

// ---------------- kernel 2: MFMA gram + distance epilogue + last-block finalize ----
// Grid (16,16): 64x64 tile, 4 waves, wave w -> 32x32 quadrant (wr=w>>1, wc=w&1).
// Per wave: 2x2 subtiles of 16x16x32 bf16 MFMA, 3-way hi/lo split, x and y.
// Fragments loaded straight from global (L2-resident, 16B/lane) -- no LDS.
// A-frag: A[m=lane&15][k=quad*8+j]; C/D: col=lane&15, row=quad*4+reg (verified map).
__global__ __launch_bounds__(256) void dist_kernel(
    const ushort* __restrict__ xh, const ushort* __restrict__ xl,
    const ushort* __restrict__ yh, const ushort* __restrict__ yl,
    const float* __restrict__ nx, const float* __restrict__ ny,
    float* __restrict__ Rx, float* __restrict__ Ry,
    float* __restrict__ sums, unsigned* __restrict__ counter,
    float* __restrict__ out) {
  int tid = threadIdx.x;
  int lane = tid & 63;
  int w = tid >> 6;
  int wr = w >> 1, wc = w & 1;
  int col = lane & 15, quad = lane >> 4;

  int aRow = blockIdx.y * 64 + wr * 32 + col;   // A operand row (m = lane&15)
  int bRow = blockIdx.x * 64 + wc * 32 + col;   // B operand row (n = lane&15)

  f32x4 accx[2][2] = {};
  f32x4 accy[2][2] = {};

  #pragma unroll 2
  for (int k0 = 0; k0 < CC; k0 += 32) {
    int kk = k0 + quad * 8;
    bf16x8 Ahx[2], Alx[2], Ahy[2], Aly[2], Bhx[2], Blx[2], Bhy[2], Bly[2];
    #pragma unroll
    for (int s = 0; s < 2; ++s) {
      size_t ao = (size_t)(aRow + s * 16) * CC + kk;
      size_t bo = (size_t)(bRow + s * 16) * CC + kk;
      Ahx[s] = *(const bf16x8*)(xh + ao);
      Alx[s] = *(const bf16x8*)(xl + ao);
      Ahy[s] = *(const bf16x8*)(yh + ao);
      Aly[s] = *(const bf16x8*)(yl + ao);
      Bhx[s] = *(const bf16x8*)(xh + bo);
      Blx[s] = *(const bf16x8*)(xl + bo);
      Bhy[s] = *(const bf16x8*)(yh + bo);
      Bly[s] = *(const bf16x8*)(yl + bo);
    }
    #pragma unroll
    for (int sr = 0; sr < 2; ++sr)
      #pragma unroll
      for (int sc = 0; sc < 2; ++sc) {
        accx[sr][sc] = __builtin_amdgcn_mfma_f32_16x16x32_bf16(Ahx[sr], Bhx[sc], accx[sr][sc], 0, 0, 0);
        accx[sr][sc] = __builtin_amdgcn_mfma_f32_16x16x32_bf16(Ahx[sr], Blx[sc], accx[sr][sc], 0, 0, 0);
        accx[sr][sc] = __builtin_amdgcn_mfma_f32_16x16x32_bf16(Alx[sr], Bhx[sc], accx[sr][sc], 0, 0, 0);
        accy[sr][sc] = __builtin_amdgcn_mfma_f32_16x16x32_bf16(Ahy[sr], Bhy[sc], accy[sr][sc], 0, 0, 0);
        accy[sr][sc] = __builtin_amdgcn_mfma_f32_16x16x32_bf16(Ahy[sr], Bly[sc], accy[sr][sc], 0, 0, 0);
        accy[sr][sc] = __builtin_amdgcn_mfma_f32_16x16x32_bf16(Aly[sr], Bhy[sc], accy[sr][sc], 0, 0, 0);
      }
  }

  // epilogue: d = sqrt(max(ni+nj-2g,0)+1e-12), accumulate row sums + products
  int rowBase = blockIdx.y * 64 + wr * 32 + quad * 4;   // + sr*16 + reg
  int colBase = blockIdx.x * 64 + wc * 32 + col;        // + sc*16
  float njx[2], njy[2];
  #pragma unroll
  for (int sc = 0; sc < 2; ++sc) { njx[sc] = nx[colBase + sc * 16]; njy[sc] = ny[colBase + sc * 16]; }

  float ab = 0.f, aa = 0.f, bb = 0.f;
  #pragma unroll
  for (int sr = 0; sr < 2; ++sr)
    #pragma unroll
    for (int r = 0; r < 4; ++r) {
      int grow = rowBase + sr * 16 + r;
      float nix = nx[grow], niy = ny[grow];
      float rsx = 0.f, rsy = 0.f;
      #pragma unroll
      for (int sc = 0; sc < 2; ++sc) {
        float dxv = sqrtf(fmaxf(nix + njx[sc] - 2.f * accx[sr][sc][r], 0.f) + 1e-12f);
        float dyv = sqrtf(fmaxf(niy + njy[sc] - 2.f * accy[sr][sc][r], 0.f) + 1e-12f);
        ab = fmaf(dxv, dyv, ab); aa = fmaf(dxv, dxv, aa); bb = fmaf(dyv, dyv, bb);
        rsx += dxv; rsy += dyv;
      }
      #pragma unroll
      for (int o = 8; o > 0; o >>= 1) { rsx += __shfl_down(rsx, o, 16); rsy += __shfl_down(rsy, o, 16); }
      if (col == 0) { atomicAdd(&Rx[grow], rsx); atomicAdd(&Ry[grow], rsy); }
    }

  #pragma unroll
  for (int o = 32; o > 0; o >>= 1) {
    ab += __shfl_down(ab, o, 64);
    aa += __shfl_down(aa, o, 64);
    bb += __shfl_down(bb, o, 64);
  }
  __shared__ float redp[3][4];
  if (lane == 0) { redp[0][w] = ab; redp[1][w] = aa; redp[2][w] = bb; }
  __syncthreads();
  if (tid == 0) {
    atomicAdd(&sums[0], redp[0][0] + redp[0][1] + redp[0][2] + redp[0][3]);
    atomicAdd(&sums[1], redp[1][0] + redp[1][1] + redp[1][2] + redp[1][3]);
    atomicAdd(&sums[2], redp[2][0] + redp[2][1] + redp[2][2] + redp[2][3]);
  }

  // -------- last block finalizes (all cross-block data via coherent atomics) ----
  __threadfence();
  __shared__ unsigned done;
  if (tid == 0) done = atomicAdd(counter, 1u);
  __syncthreads();
  if (done != 255) return;

  double sx = 0, sy = 0, srr = 0, sxx = 0, syy = 0;
  #pragma unroll
  for (int i = 0; i < 4; ++i) {
    int row = tid * 4 + i;
    double rx = (double)atomicAdd(&Rx[row], 0.0f);   // coherent read
    double ry = (double)atomicAdd(&Ry[row], 0.0f);
    sx += rx; sy += ry; srr += rx * ry; sxx += rx * rx; syy += ry * ry;
  }
  #pragma unroll
  for (int o = 32; o > 0; o >>= 1) {
    sx += __shfl_down(sx, o, 64);  sy += __shfl_down(sy, o, 64);
    srr += __shfl_down(srr, o, 64); sxx += __shfl_down(sxx, o, 64);
    syy += __shfl_down(syy, o, 64);
  }
  __shared__ double td[5][4];
  if (lane == 0) { td[0][w] = sx; td[1][w] = sy; td[2][w] = srr; td[3][w] = sxx; td[4][w] = syy; }
  __syncthreads();
  if (tid == 0) {
    sx  = td[0][0] + td[0][1] + td[0][2] + td[0][3];
    sy  = td[1][0] + td[1][1] + td[1][2] + td[1][3];
    srr = td[2][0] + td[2][1] + td[2][2] + td[2][3];
    sxx = td[3][0] + td[3][1] + td[3][2] + td[3][3];
    syy = td[4][0] + td[4][1] + td[4][2] + td[4][3];
    double abt = (double)atomicAdd(&sums[0], 0.0f);
    double aat = (double)atomicAdd(&sums[1], 0.0f);
    double bbt = (double)atomicAdd(&sums[2], 0.0f);
    const double n = (double)NN, n2 = n * n;
    double AB = abt - (2.0 / n) * srr + sx * sy / n2;
    double AA = aat - (2.0 / n) * sxx + sx * sx / n2;
    double BB = bbt - (2.0 / n) * syy + sy * sy / n2;
    double xy = AB / n2, xx = AA / n2, yy = BB / n2;
    double r = xy / sqrt(xx * yy + 1e-9);
    out[0] = (float)(1.0 - r);
  }
}

extern "C" void kernel_launch(void* const* d_in, const int* in_sizes, int n_in,
                              void* d_out, int out_size, void* d_ws, size_t ws_size,
                              hipStream_t stream) {
  const float* in0 = (const float*)d_in[0];   // output_1 (N,T,C) fp32
  const float* in1 = (const float*)d_in[1];   // feature  (N,T,C) fp32

  char* ws = (char*)d_ws;
  const size_t SZ = (size_t)NN * CC * sizeof(ushort);     // 512 KB per bf16 array
  ushort* xh = (ushort*)(ws);
  ushort* xl = (ushort*)(ws + SZ);
  ushort* yh = (ushort*)(ws + 2 * SZ);
  ushort* yl = (ushort*)(ws + 3 * SZ);
  float* nx  = (float*)(ws + 4 * SZ);                      // 4 KB
  float* ny  = (float*)(ws + 4 * SZ + 4096);               // 4 KB
  float* Rx  = (float*)(ws + 4 * SZ + 8192);               // 4 KB (zeroed)
  float* Ry  = (float*)(ws + 4 * SZ + 12288);              // 4 KB (zeroed)
  float* sums = (float*)(ws + 4 * SZ + 16384);             // 3 floats (zeroed)
  unsigned* counter = (unsigned*)(ws + 4 * SZ + 16384 + 64); // 1 uint (zeroed)

  mean_norm_kernel<<<2 * NN, 256, 0, stream>>>(in0, in1, xh, xl, yh, yl, nx, ny,
                                               Rx, Ry, sums, counter);
  dist_kernel<<<dim3(16, 16), 256, 0, stream>>>(xh, xl, yh, yl, nx, ny,
                                                Rx, Ry, sums, counter, (float*)d_out);
}